// Round 1
// 119.415 us; speedup vs baseline: 1.0995x; 1.0995x over previous
//
#include <hip/hip_runtime.h>
#include <math.h>

typedef __attribute__((ext_vector_type(8))) short  short8;    // 8 bf16 = 4 VGPRs
typedef __attribute__((ext_vector_type(4))) float  floatx4;   // MFMA C/D

#define MFMA16(a, b, c) __builtin_amdgcn_mfma_f32_16x16x32_bf16(a, b, c, 0, 0, 0)

constexpr int NSEQ = 2048;
constexpr int DIN  = 768;
constexpr int NH   = 12;
constexpr size_t NX = (size_t)2 * NSEQ * DIN;   // x elems  = 3,145,728
constexpr size_t NW = (size_t)DIN * DIN;        // Wq elems =   589,824
constexpr float QSCALE = 0.18033688011112042f;  // log2(e)/8

__device__ __forceinline__ ushort f2bf(float f) {   // RNE fp32 -> bf16
    unsigned u = __float_as_uint(f);
    u += 0x7FFF + ((u >> 16) & 1);
    return (ushort)(u >> 16);
}
__device__ __forceinline__ float bf2f(ushort u) {
    return __uint_as_float(((unsigned)u) << 16);
}
// one instruction packs two fp32 -> 2xbf16 (RNE); replaces ~8 VALU ops
__device__ __forceinline__ unsigned cvt_pk_bf16(float lo, float hi) {
    unsigned r;
    asm("v_cvt_pk_bf16_f32 %0, %1, %2" : "=v"(r) : "v"(lo), "v"(hi));
    return r;
}

// -----------------------------------------------------------------------------
// Kernel 0: convert x and Wq to bf16 (contiguous in ws). Memory-bound, ~4 us.
// -----------------------------------------------------------------------------
__global__ __launch_bounds__(256)
void cvt_bf16(const float* __restrict__ x, const float* __restrict__ Wq,
              ushort* __restrict__ dst)
{
    size_t i = ((size_t)blockIdx.x * 256 + threadIdx.x) * 8;
    const float* s = (i < NX) ? (x + i) : (Wq + (i - NX));
    float4 f0 = ((const float4*)s)[0];
    float4 f1 = ((const float4*)s)[1];
    short8 o;
    o[0] = (short)f2bf(f0.x); o[1] = (short)f2bf(f0.y);
    o[2] = (short)f2bf(f0.z); o[3] = (short)f2bf(f0.w);
    o[4] = (short)f2bf(f1.x); o[5] = (short)f2bf(f1.y);
    o[6] = (short)f2bf(f1.z); o[7] = (short)f2bf(f1.w);
    *(short8*)(dst + i) = o;
}

// -----------------------------------------------------------------------------
// Kernel 1: h = xb @ wb^T. BM=64 x BN=64, BK=64 -> grid (64,12) = 768 blocks,
// exactly 3/CU FULLY RESIDENT (old 64x128 grid was 384 blocks = 1.5/CU,
// latency-starved). 4 waves, each 32x32 out. Same reg-prefetch pipeline.
// -----------------------------------------------------------------------------
__global__ __launch_bounds__(256, 3)
void qkv_mfma(const ushort* __restrict__ xb, const ushort* __restrict__ wb,
              ushort* __restrict__ h)
{
    __shared__ ushort As[64 * 72];    // [row][k] pitch 72
    __shared__ ushort Bs[64 * 72];    // [col][k]

    const int tid  = threadIdx.x;
    const int w    = tid >> 6;
    const int lane = tid & 63;
    const int m    = lane & 15;
    const int quad = lane >> 4;
    const int r0   = blockIdx.x * 64;
    const int c0   = blockIdx.y * 64;
    const int mrow0 = (w & 1) * 32;
    const int ncol0 = (w >> 1) * 32;

    floatx4 C[2][2] = {};
    short8 ar[2], br[2];

    // prefetch k-tile 0 (A and B tiles are each 64x64 = 512 short8s / 256 thr)
    #pragma unroll
    for (int i = 0; i < 2; ++i) {
        int id = tid + i * 256;
        ar[i] = *(const short8*)(xb + (size_t)(r0 + (id >> 3)) * DIN + (id & 7) * 8);
        br[i] = *(const short8*)(wb + (size_t)(c0 + (id >> 3)) * DIN + (id & 7) * 8);
    }

    for (int kk = 0; kk < 12; ++kk) {
        __syncthreads();
        #pragma unroll
        for (int i = 0; i < 2; ++i) {
            int id = tid + i * 256;
            *(short8*)&As[(id >> 3) * 72 + (id & 7) * 8] = ar[i];
            *(short8*)&Bs[(id >> 3) * 72 + (id & 7) * 8] = br[i];
        }
        if (kk < 11) {                         // prefetch next tile
            const int k0 = (kk + 1) * 64;
            #pragma unroll
            for (int i = 0; i < 2; ++i) {
                int id = tid + i * 256;
                ar[i] = *(const short8*)(xb + (size_t)(r0 + (id >> 3)) * DIN + k0 + (id & 7) * 8);
                br[i] = *(const short8*)(wb + (size_t)(c0 + (id >> 3)) * DIN + k0 + (id & 7) * 8);
            }
        }
        __syncthreads();

        #pragma unroll
        for (int kt2 = 0; kt2 < 2; ++kt2) {
            short8 a0 = *(const short8*)&As[(mrow0 + m)      * 72 + kt2 * 32 + quad * 8];
            short8 a1 = *(const short8*)&As[(mrow0 + 16 + m) * 72 + kt2 * 32 + quad * 8];
            short8 b0 = *(const short8*)&Bs[(ncol0 + m)      * 72 + kt2 * 32 + quad * 8];
            short8 b1 = *(const short8*)&Bs[(ncol0 + 16 + m) * 72 + kt2 * 32 + quad * 8];
            C[0][0] = MFMA16(a0, b0, C[0][0]);
            C[0][1] = MFMA16(a0, b1, C[0][1]);
            C[1][0] = MFMA16(a1, b0, C[1][0]);
            C[1][1] = MFMA16(a1, b1, C[1][1]);
        }
    }

    #pragma unroll
    for (int mt = 0; mt < 2; ++mt)
        #pragma unroll
        for (int nt = 0; nt < 2; ++nt) {
            int cg = c0 + ncol0 + nt * 16 + m;
            int head = cg >> 6, d = cg & 63;
            #pragma unroll
            for (int r = 0; r < 4; ++r) {
                int rg = r0 + mrow0 + mt * 16 + quad * 4 + r;
                int b = rg >> 11, q = rg & 2047;
                h[((size_t)(b * NH + head) * NSEQ + q) * 64 + d] = f2bf(C[mt][nt][r]);
            }
        }
}

// -----------------------------------------------------------------------------
// Kernel 2: causal flash attention, K=V=h. Block = 32 q (2 waves x 16 q),
// 128 threads, grid (64,24) = 1536 blocks = 6/CU fully resident.
// qt mapping: CU c hosts blocks {c+256k}, k=0..5 -> same x, t=(bh>>2)=k each
// once. qt = (t&1) ? x : 63-x gives 3 complementary pairs per CU ->
// EXACTLY 99 k-tile units on every CU (old grid: all blocks on a CU shared
// one qt -> 2x CU imbalance -> 14.6% occupancy).
// P pack uses v_cvt_pk_bf16_f32 (8 instr vs ~64 VALU ops of scalar f2bf).
// -----------------------------------------------------------------------------
__global__ __launch_bounds__(128, 3)
void attn_mfma(const ushort* __restrict__ h, float* __restrict__ out)
{
    __shared__ ushort Ks[64 * 72];      // [key][d]
    __shared__ ushort Vt[64 * 72];      // [d][key]
    __shared__ ushort Ps[2 * 16 * 72];  // per-wave P [q][key]

    const int tid  = threadIdx.x;
    const int w    = tid >> 6;          // 0..1
    const int lane = tid & 63;
    const int m    = lane & 15;
    const int quad = lane >> 4;

    const int xi = blockIdx.x;          // 0..63
    const int bh = blockIdx.y;          // 0..23
    const int t  = bh >> 2;             // 0..5 : sweeps 0..5 across a CU's blocks
    const int qt = (t & 1) ? xi : (63 - xi);
    const int q0 = qt * 32;
    const int wq = q0 + w * 16;         // this wave's q base
    const int nkt = (qt >> 1) + 1;      // # of 64-key tiles
    const ushort* __restrict__ Hh = h + (size_t)bh * NSEQ * 64;

    // Q fragments (B-operand: n=q=m, k=d), pre-scaled by log2(e)/8
    short8 qa[2];
    #pragma unroll
    for (int kt2 = 0; kt2 < 2; ++kt2) {
        short8 raw = *(const short8*)(Hh + (size_t)(wq + m) * 64 + kt2 * 32 + quad * 8);
        #pragma unroll
        for (int j = 0; j < 8; ++j)
            qa[kt2][j] = (short)f2bf(bf2f((ushort)raw[j]) * QSCALE);
    }

    floatx4 O[4] = {};                  // O^T tiles: d = mt*16+quad*4+r, q = m
    float lacc = 0.0f;
    ushort* Psw = Ps + w * 16 * 72;

    const int kr2  = (tid & 31) * 2;    // staging: 2 adjacent key rows
    const int part = tid >> 5;          // d-chunk 0..3 (16 d each)
    const int db   = part * 16;

    short8 pre[4];                      // [row kr2 lo|hi, row kr2+1 lo|hi]
    {
        const ushort* src = Hh + (size_t)kr2 * 64 + db;
        pre[0] = *(const short8*)src;
        pre[1] = *(const short8*)(src + 8);
        pre[2] = *(const short8*)(src + 64);
        pre[3] = *(const short8*)(src + 72);
    }

    for (int kt = 0; kt < nkt; ++kt) {
        __syncthreads();                // Ks/Vt free for overwrite
        *(short8*)&Ks[kr2       * 72 + db]     = pre[0];
        *(short8*)&Ks[kr2       * 72 + db + 8] = pre[1];
        *(short8*)&Ks[(kr2 + 1) * 72 + db]     = pre[2];
        *(short8*)&Ks[(kr2 + 1) * 72 + db + 8] = pre[3];
        union { short8 v; ushort u[8]; } a0, a1, b0, b1;
        a0.v = pre[0]; a1.v = pre[1]; b0.v = pre[2]; b1.v = pre[3];
        #pragma unroll
        for (int i = 0; i < 8; ++i) {
            *(unsigned*)&Vt[(db + i)     * 72 + kr2] = (unsigned)a0.u[i] | ((unsigned)b0.u[i] << 16);
            *(unsigned*)&Vt[(db + 8 + i) * 72 + kr2] = (unsigned)a1.u[i] | ((unsigned)b1.u[i] << 16);
        }
        if (kt + 1 < nkt) {             // prefetch next K tile
            const ushort* src = Hh + (size_t)((kt + 1) * 64 + kr2) * 64 + db;
            pre[0] = *(const short8*)src;
            pre[1] = *(const short8*)(src + 8);
            pre[2] = *(const short8*)(src + 64);
            pre[3] = *(const short8*)(src + 72);
        }
        __syncthreads();

        // ---- S^T = K Q^T : rows=key, cols=q ----
        floatx4 S[4] = {};
        #pragma unroll
        for (int kt2 = 0; kt2 < 2; ++kt2)
            #pragma unroll
            for (int mt = 0; mt < 4; ++mt) {
                short8 ka = *(const short8*)&Ks[(mt * 16 + m) * 72 + kt2 * 32 + quad * 8];
                S[mt] = MFMA16(ka, qa[kt2], S[mt]);
            }

        // ---- exp2 + packed P write (cvt_pk) + l accumulate ----
        const int lim = wq + m - kt * 64;   // causal limit in-tile
        if (kt == nkt - 1) {                // diagonal tile: causal mask
            #pragma unroll
            for (int mt = 0; mt < 4; ++mt) {
                float p0 = (mt * 16 + quad * 4 + 0 <= lim) ? exp2f(S[mt][0]) : 0.0f;
                float p1 = (mt * 16 + quad * 4 + 1 <= lim) ? exp2f(S[mt][1]) : 0.0f;
                float p2 = (mt * 16 + quad * 4 + 2 <= lim) ? exp2f(S[mt][2]) : 0.0f;
                float p3 = (mt * 16 + quad * 4 + 3 <= lim) ? exp2f(S[mt][3]) : 0.0f;
                lacc += (p0 + p1) + (p2 + p3);
                uint2 pw;
                pw.x = cvt_pk_bf16(p0, p1);
                pw.y = cvt_pk_bf16(p2, p3);
                *(uint2*)&Psw[m * 72 + mt * 16 + quad * 4] = pw;
            }
        } else {                            // interior tile: no mask
            #pragma unroll
            for (int mt = 0; mt < 4; ++mt) {
                float p0 = exp2f(S[mt][0]);
                float p1 = exp2f(S[mt][1]);
                float p2 = exp2f(S[mt][2]);
                float p3 = exp2f(S[mt][3]);
                lacc += (p0 + p1) + (p2 + p3);
                uint2 pw;
                pw.x = cvt_pk_bf16(p0, p1);
                pw.y = cvt_pk_bf16(p2, p3);
                *(uint2*)&Psw[m * 72 + mt * 16 + quad * 4] = pw;
            }
        }

        // ---- O^T += V^T P^T (same-wave LDS, no barrier needed) ----
        #pragma unroll
        for (int kt2 = 0; kt2 < 2; ++kt2) {
            short8 pb = *(const short8*)&Psw[m * 72 + kt2 * 32 + quad * 8];
            #pragma unroll
            for (int mt = 0; mt < 4; ++mt) {
                short8 va = *(const short8*)&Vt[(mt * 16 + m) * 72 + kt2 * 32 + quad * 8];
                O[mt] = MFMA16(va, pb, O[mt]);
            }
        }
    }

    // ---- l reduce across the 4 quads holding the same q ----
    lacc += __shfl_xor(lacc, 16);
    lacc += __shfl_xor(lacc, 32);
    float linv = 1.0f / lacc;

    // ---- store out[bh][d][q] (reference's transposed layout), 64B segments ----
    #pragma unroll
    for (int mt = 0; mt < 4; ++mt)
        #pragma unroll
        for (int r = 0; r < 4; ++r) {
            int d = mt * 16 + quad * 4 + r;
            out[((size_t)bh * 64 + d) * NSEQ + q0 + w * 16 + m] = O[mt][r] * linv;
        }
}

extern "C" void kernel_launch(void* const* d_in, const int* in_sizes, int n_in,
                              void* d_out, int out_size, void* d_ws, size_t ws_size,
                              hipStream_t stream)
{
    (void)in_sizes; (void)n_in; (void)out_size; (void)ws_size;
    const float* x  = (const float*)d_in[0];
    const float* Wq = (const float*)d_in[1];
    float* out = (float*)d_out;

    ushort* xb = (ushort*)d_ws;                 // 6.29 MB
    ushort* wb = xb + NX;                       // 1.18 MB
    ushort* hb = wb + NW;                       // 6.29 MB  (ws is 256 MiB)

    cvt_bf16<<<dim3((NX + NW) / (8 * 256)), dim3(256), 0, stream>>>(x, Wq, xb);
    qkv_mfma<<<dim3(64, 12), dim3(256), 0, stream>>>(xb, wb, hb);
    attn_mfma<<<dim3(64, 24), dim3(128), 0, stream>>>(hb, out);
}

// Round 3
// 116.430 us; speedup vs baseline: 1.1277x; 1.0256x over previous
//
#include <hip/hip_runtime.h>
#include <math.h>

typedef __attribute__((ext_vector_type(8))) short  short8;    // 8 bf16 = 4 VGPRs
typedef __attribute__((ext_vector_type(4))) float  floatx4;   // MFMA C/D

#define MFMA16(a, b, c) __builtin_amdgcn_mfma_f32_16x16x32_bf16(a, b, c, 0, 0, 0)

constexpr int NSEQ = 2048;
constexpr int DIN  = 768;
constexpr int NH   = 12;
constexpr size_t NX = (size_t)2 * NSEQ * DIN;   // x elems  = 3,145,728
constexpr size_t NW = (size_t)DIN * DIN;        // Wq elems =   589,824
constexpr float QSCALE = 0.18033688011112042f;  // log2(e)/8

__device__ __forceinline__ ushort f2bf(float f) {   // RNE fp32 -> bf16
    unsigned u = __float_as_uint(f);
    u += 0x7FFF + ((u >> 16) & 1);
    return (ushort)(u >> 16);
}
__device__ __forceinline__ float bf2f(ushort u) {
    return __uint_as_float(((unsigned)u) << 16);
}
__device__ __forceinline__ unsigned cvt_pk_bf16(float lo, float hi) {
    unsigned r;
    asm("v_cvt_pk_bf16_f32 %0, %1, %2" : "=v"(r) : "v"(lo), "v"(hi));
    return r;
}
// LDS-only barrier: orders ds ops across the block WITHOUT draining vmcnt.
// __syncthreads() emits s_waitcnt vmcnt(0) before s_barrier, which kills the
// register prefetch (loads for tile k+1 drained at the barrier of tile k).
__device__ __forceinline__ void bar_lds() {
    asm volatile("s_waitcnt lgkmcnt(0)" ::: "memory");
    __builtin_amdgcn_s_barrier();
}

// -----------------------------------------------------------------------------
// Kernel 0: convert x and Wq to bf16 (contiguous in ws). Memory-bound, ~4 us.
// -----------------------------------------------------------------------------
__global__ __launch_bounds__(256)
void cvt_bf16(const float* __restrict__ x, const float* __restrict__ Wq,
              ushort* __restrict__ dst)
{
    size_t i = ((size_t)blockIdx.x * 256 + threadIdx.x) * 8;
    const float* s = (i < NX) ? (x + i) : (Wq + (i - NX));
    float4 f0 = ((const float4*)s)[0];
    float4 f1 = ((const float4*)s)[1];
    short8 o;
    o[0] = (short)f2bf(f0.x); o[1] = (short)f2bf(f0.y);
    o[2] = (short)f2bf(f0.z); o[3] = (short)f2bf(f0.w);
    o[4] = (short)f2bf(f1.x); o[5] = (short)f2bf(f1.y);
    o[6] = (short)f2bf(f1.z); o[7] = (short)f2bf(f1.w);
    *(short8*)(dst + i) = o;
}

// -----------------------------------------------------------------------------
// Kernel 1: h = xb @ wb^T. BM=64 x BN=64, grid (64,12) = 768 blocks, 3/CU.
// Identical to round-1 EXCEPT: lgkmcnt-only barriers so the register prefetch
// for tile k+1 stays in flight across the whole compute phase of tile k.
// -----------------------------------------------------------------------------
__global__ __launch_bounds__(256, 3)
void qkv_mfma(const ushort* __restrict__ xb, const ushort* __restrict__ wb,
              ushort* __restrict__ h)
{
    __shared__ ushort As[64 * 72];    // [row][k] pitch 72
    __shared__ ushort Bs[64 * 72];    // [col][k]

    const int tid  = threadIdx.x;
    const int w    = tid >> 6;
    const int lane = tid & 63;
    const int m    = lane & 15;
    const int quad = lane >> 4;
    const int r0   = blockIdx.x * 64;
    const int c0   = blockIdx.y * 64;
    const int mrow0 = (w & 1) * 32;
    const int ncol0 = (w >> 1) * 32;

    floatx4 C[2][2] = {};
    short8 ar[2], br[2];

    #pragma unroll
    for (int i = 0; i < 2; ++i) {
        int id = tid + i * 256;
        ar[i] = *(const short8*)(xb + (size_t)(r0 + (id >> 3)) * DIN + (id & 7) * 8);
        br[i] = *(const short8*)(wb + (size_t)(c0 + (id >> 3)) * DIN + (id & 7) * 8);
    }

    for (int kk = 0; kk < 12; ++kk) {
        bar_lds();                      // prior reads consumed; no vmcnt drain
        #pragma unroll
        for (int i = 0; i < 2; ++i) {
            int id = tid + i * 256;
            *(short8*)&As[(id >> 3) * 72 + (id & 7) * 8] = ar[i];
            *(short8*)&Bs[(id >> 3) * 72 + (id & 7) * 8] = br[i];
        }
        if (kk < 11) {                  // prefetch next tile (stays in flight)
            const int k0 = (kk + 1) * 64;
            #pragma unroll
            for (int i = 0; i < 2; ++i) {
                int id = tid + i * 256;
                ar[i] = *(const short8*)(xb + (size_t)(r0 + (id >> 3)) * DIN + k0 + (id & 7) * 8);
                br[i] = *(const short8*)(wb + (size_t)(c0 + (id >> 3)) * DIN + k0 + (id & 7) * 8);
            }
        }
        bar_lds();                      // writes visible; loads NOT drained

        #pragma unroll
        for (int kt2 = 0; kt2 < 2; ++kt2) {
            short8 a0 = *(const short8*)&As[(mrow0 + m)      * 72 + kt2 * 32 + quad * 8];
            short8 a1 = *(const short8*)&As[(mrow0 + 16 + m) * 72 + kt2 * 32 + quad * 8];
            short8 b0 = *(const short8*)&Bs[(ncol0 + m)      * 72 + kt2 * 32 + quad * 8];
            short8 b1 = *(const short8*)&Bs[(ncol0 + 16 + m) * 72 + kt2 * 32 + quad * 8];
            C[0][0] = MFMA16(a0, b0, C[0][0]);
            C[0][1] = MFMA16(a0, b1, C[0][1]);
            C[1][0] = MFMA16(a1, b0, C[1][0]);
            C[1][1] = MFMA16(a1, b1, C[1][1]);
        }
    }

    #pragma unroll
    for (int mt = 0; mt < 2; ++mt)
        #pragma unroll
        for (int nt = 0; nt < 2; ++nt) {
            int cg = c0 + ncol0 + nt * 16 + m;
            int head = cg >> 6, d = cg & 63;
            #pragma unroll
            for (int r = 0; r < 4; ++r) {
                int rg = r0 + mrow0 + mt * 16 + quad * 4 + r;
                int b = rg >> 11, q = rg & 2047;
                h[((size_t)(b * NH + head) * NSEQ + q) * 64 + d] = f2bf(C[mt][nt][r]);
            }
        }
}

// -----------------------------------------------------------------------------
// Kernel 2: causal flash attention, K=V=h. Block = 2 waves x 16 q, and each
// block owns the complementary q-tile PAIR (qt, 63-qt): k-tile counts sum to
// EXACTLY 33 for every pair -> all 768 blocks (grid 32x24, 3/CU) do identical
// work regardless of dispatch order. No drain tail (round-1: 17% avg occupancy
// because each CU held 3 long + 3 trivial blocks). lgkmcnt-only barriers keep
// the K-tile prefetch in flight across S-MFMA/softmax/PV.
// -----------------------------------------------------------------------------
__global__ __launch_bounds__(128, 3)
void attn_mfma(const ushort* __restrict__ h, float* __restrict__ out)
{
    __shared__ ushort Ks[64 * 72];      // [key][d]
    __shared__ ushort Vt[64 * 72];      // [d][key]
    __shared__ ushort Ps[2 * 16 * 72];  // per-wave P [q][key]

    const int tid  = threadIdx.x;
    const int w    = tid >> 6;          // 0..1
    const int lane = tid & 63;
    const int m    = lane & 15;
    const int quad = lane >> 4;

    const int p  = blockIdx.x;          // pair id 0..31
    const int bh = blockIdx.y;          // 0..23
    const ushort* __restrict__ Hh = h + (size_t)bh * NSEQ * 64;
    ushort* Psw = Ps + w * 16 * 72;

    const int kr2  = (tid & 31) * 2;    // staging: 2 adjacent key rows
    const int part = tid >> 5;          // d-chunk 0..3 (16 d each)
    const int db   = part * 16;

    #pragma unroll 1
    for (int half = 0; half < 2; ++half) {
        const int qt  = half ? p : (63 - p);
        const int q0  = qt * 32;
        const int wq  = q0 + w * 16;    // this wave's q base
        const int nkt = (qt >> 1) + 1;  // # of 64-key tiles

        // Q fragments (B-operand: n=q=m, k=d), pre-scaled by log2(e)/8
        short8 qa[2];
        #pragma unroll
        for (int kt2 = 0; kt2 < 2; ++kt2) {
            short8 raw = *(const short8*)(Hh + (size_t)(wq + m) * 64 + kt2 * 32 + quad * 8);
            #pragma unroll
            for (int j = 0; j < 8; ++j)
                qa[kt2][j] = (short)f2bf(bf2f((ushort)raw[j]) * QSCALE);
        }

        floatx4 O[4] = {};              // O^T tiles: d = mt*16+quad*4+r, q = m
        float lacc = 0.0f;

        short8 pre[4];                  // prefetched K rows kr2, kr2+1
        {
            const ushort* src = Hh + (size_t)kr2 * 64 + db;
            pre[0] = *(const short8*)src;
            pre[1] = *(const short8*)(src + 8);
            pre[2] = *(const short8*)(src + 64);
            pre[3] = *(const short8*)(src + 72);
        }

        for (int kt = 0; kt < nkt; ++kt) {
            bar_lds();                  // Ks/Vt free for overwrite (no vmcnt drain)
            *(short8*)&Ks[kr2       * 72 + db]     = pre[0];
            *(short8*)&Ks[kr2       * 72 + db + 8] = pre[1];
            *(short8*)&Ks[(kr2 + 1) * 72 + db]     = pre[2];
            *(short8*)&Ks[(kr2 + 1) * 72 + db + 8] = pre[3];
            union { short8 v; ushort u[8]; } a0, a1, b0, b1;
            a0.v = pre[0]; a1.v = pre[1]; b0.v = pre[2]; b1.v = pre[3];
            #pragma unroll
            for (int i = 0; i < 8; ++i) {
                *(unsigned*)&Vt[(db + i)     * 72 + kr2] = (unsigned)a0.u[i] | ((unsigned)b0.u[i] << 16);
                *(unsigned*)&Vt[(db + 8 + i) * 72 + kr2] = (unsigned)a1.u[i] | ((unsigned)b1.u[i] << 16);
            }
            if (kt + 1 < nkt) {         // prefetch next K tile (stays in flight)
                const ushort* src = Hh + (size_t)((kt + 1) * 64 + kr2) * 64 + db;
                pre[0] = *(const short8*)src;
                pre[1] = *(const short8*)(src + 8);
                pre[2] = *(const short8*)(src + 64);
                pre[3] = *(const short8*)(src + 72);
            }
            bar_lds();

            // ---- S^T = K Q^T : rows=key, cols=q ----
            floatx4 S[4] = {};
            #pragma unroll
            for (int kt2 = 0; kt2 < 2; ++kt2)
                #pragma unroll
                for (int mt = 0; mt < 4; ++mt) {
                    short8 ka = *(const short8*)&Ks[(mt * 16 + m) * 72 + kt2 * 32 + quad * 8];
                    S[mt] = MFMA16(ka, qa[kt2], S[mt]);
                }

            // ---- exp2 + packed P write (cvt_pk) + l accumulate ----
            const int lim = wq + m - kt * 64;   // causal limit in-tile
            if (kt == nkt - 1) {                // diagonal tile: causal mask
                #pragma unroll
                for (int mt = 0; mt < 4; ++mt) {
                    float p0 = (mt * 16 + quad * 4 + 0 <= lim) ? exp2f(S[mt][0]) : 0.0f;
                    float p1 = (mt * 16 + quad * 4 + 1 <= lim) ? exp2f(S[mt][1]) : 0.0f;
                    float p2 = (mt * 16 + quad * 4 + 2 <= lim) ? exp2f(S[mt][2]) : 0.0f;
                    float p3 = (mt * 16 + quad * 4 + 3 <= lim) ? exp2f(S[mt][3]) : 0.0f;
                    lacc += (p0 + p1) + (p2 + p3);
                    uint2 pw;
                    pw.x = cvt_pk_bf16(p0, p1);
                    pw.y = cvt_pk_bf16(p2, p3);
                    *(uint2*)&Psw[m * 72 + mt * 16 + quad * 4] = pw;
                }
            } else {                            // interior tile: no mask
                #pragma unroll
                for (int mt = 0; mt < 4; ++mt) {
                    float p0 = exp2f(S[mt][0]);
                    float p1 = exp2f(S[mt][1]);
                    float p2 = exp2f(S[mt][2]);
                    float p3 = exp2f(S[mt][3]);
                    lacc += (p0 + p1) + (p2 + p3);
                    uint2 pw;
                    pw.x = cvt_pk_bf16(p0, p1);
                    pw.y = cvt_pk_bf16(p2, p3);
                    *(uint2*)&Psw[m * 72 + mt * 16 + quad * 4] = pw;
                }
            }

            // ---- O^T += V^T P^T (same-wave LDS, no barrier needed) ----
            #pragma unroll
            for (int kt2 = 0; kt2 < 2; ++kt2) {
                short8 pb = *(const short8*)&Psw[m * 72 + kt2 * 32 + quad * 8];
                #pragma unroll
                for (int mt = 0; mt < 4; ++mt) {
                    short8 va = *(const short8*)&Vt[(mt * 16 + m) * 72 + kt2 * 32 + quad * 8];
                    O[mt] = MFMA16(va, pb, O[mt]);
                }
            }
        }

        // ---- l reduce across the 4 quads holding the same q ----
        lacc += __shfl_xor(lacc, 16);
        lacc += __shfl_xor(lacc, 32);
        float linv = 1.0f / lacc;

        // ---- store out[bh][d][q] (reference's transposed layout) ----
        #pragma unroll
        for (int mt = 0; mt < 4; ++mt)
            #pragma unroll
            for (int r = 0; r < 4; ++r) {
                int d = mt * 16 + quad * 4 + r;
                out[((size_t)bh * 64 + d) * NSEQ + q0 + w * 16 + m] = O[mt][r] * linv;
            }
    }
}

extern "C" void kernel_launch(void* const* d_in, const int* in_sizes, int n_in,
                              void* d_out, int out_size, void* d_ws, size_t ws_size,
                              hipStream_t stream)
{
    (void)in_sizes; (void)n_in; (void)out_size; (void)ws_size;
    const float* x  = (const float*)d_in[0];
    const float* Wq = (const float*)d_in[1];
    float* out = (float*)d_out;

    ushort* xb = (ushort*)d_ws;                 // 6.29 MB
    ushort* wb = xb + NX;                       // 1.18 MB
    ushort* hb = wb + NW;                       // 6.29 MB  (ws is 256 MiB)

    cvt_bf16<<<dim3((NX + NW) / (8 * 256)), dim3(256), 0, stream>>>(x, Wq, xb);
    qkv_mfma<<<dim3(64, 12), dim3(256), 0, stream>>>(xb, wb, hb);
    attn_mfma<<<dim3(32, 24), dim3(128), 0, stream>>>(hb, out);
}